// Round 1
// baseline (828.745 us; speedup 1.0000x reference)
//
#include <hip/hip_runtime.h>
#include <hip/hip_bf16.h>

#define S_LEN 2048
#define DM 1024

typedef __attribute__((ext_vector_type(8))) short s16x8;
typedef __attribute__((ext_vector_type(4))) float f32x4;
typedef __attribute__((ext_vector_type(4))) ushort u16x4;

__device__ __forceinline__ ushort f2bf(float f){
  union { float f; unsigned u; } v; v.f = f;
  unsigned r = (v.u + 0x7FFFu + ((v.u >> 16) & 1u)) >> 16;
  return (ushort)r;
}

__device__ __forceinline__ f32x4 mfma16(s16x8 a, s16x8 b, f32x4 c){
  return __builtin_amdgcn_mfma_f32_16x16x32_bf16(a, b, c, 0, 0, 0);
}

// ---------------- LayerNorm: fp32 row -> bf16 row ----------------
__global__ __launch_bounds__(256) void ln_kernel(const float* __restrict__ x,
    const float* __restrict__ g, const float* __restrict__ be, ushort* __restrict__ o){
  int row = blockIdx.x;
  int tid = threadIdx.x;
  const float* xr = x + (size_t)row*DM;
  float4 xv = *(const float4*)(xr + tid*4);
  float s  = xv.x+xv.y+xv.z+xv.w;
  float s2 = xv.x*xv.x+xv.y*xv.y+xv.z*xv.z+xv.w*xv.w;
  for (int m=1;m<64;m<<=1){ s += __shfl_xor(s,m); s2 += __shfl_xor(s2,m); }
  __shared__ float red[8];
  int w = tid>>6, l = tid&63;
  if (l==0){ red[w]=s; red[4+w]=s2; }
  __syncthreads();
  float ts = red[0]+red[1]+red[2]+red[3];
  float t2 = red[4]+red[5]+red[6]+red[7];
  float mu  = ts*(1.0f/DM);
  float var = t2*(1.0f/DM) - mu*mu;
  float rs  = rsqrtf(var + 1e-5f);
  float vals[4] = {xv.x,xv.y,xv.z,xv.w};
  const float* gp = g + tid*4;
  const float* bp = be + tid*4;
  u16x4 ov;
  #pragma unroll
  for (int j=0;j<4;j++) ov[j] = f2bf((vals[j]-mu)*rs*gp[j] + bp[j]);
  *(u16x4*)(o + (size_t)row*DM + tid*4) = ov;
}

// ---------------- Weight transpose + bf16 convert: in[K][N] -> out[N][K=1024] ----------------
__global__ __launch_bounds__(256) void wtr_kernel(const float* __restrict__ in,
    ushort* __restrict__ out, int nshift){
  int idx = blockIdx.x*256 + threadIdx.x;
  int nn = idx & ((1<<nshift)-1);
  int kk = idx >> nshift;
  out[((size_t)nn<<10) + kk] = f2bf(in[((size_t)kk<<nshift) + nn]);
}

// ---------------- GEMM: C[M x N] = A[M x K] * BT[N x K]^T + bias (optional RoPE epilogue) ----------------
template<bool ROPE, bool F32OUT>
__global__ __launch_bounds__(256) void gemm_kernel(
    const ushort* __restrict__ A, const ushort* __restrict__ BT,
    const float* __restrict__ bias, void* __restrict__ Cv,
    int N, int K){
  __shared__ ushort Als[64*40];
  __shared__ ushort Bls[64*40];
  int tid = threadIdx.x;
  int w = tid>>6, l = tid&63, lg = l>>4, li = l&15;
  int mbase = blockIdx.y*64, nbase = blockIdx.x*64;
  f32x4 acc[4];
  #pragma unroll
  for (int c=0;c<4;c++) acc[c] = (f32x4){0.f,0.f,0.f,0.f};
  int srow = tid>>2, scg = (tid&3)*8;
  const ushort* Ap = A  + (size_t)(mbase+srow)*K + scg;
  const ushort* Bp = BT + (size_t)(nbase+srow)*K + scg;
  for (int kk=0; kk<K; kk+=32){
    __syncthreads();
    *(s16x8*)&Als[srow*40 + scg] = *(const s16x8*)(Ap + kk);
    *(s16x8*)&Bls[srow*40 + scg] = *(const s16x8*)(Bp + kk);
    __syncthreads();
    s16x8 af = *(const s16x8*)&Als[(16*w+li)*40 + 8*lg];
    #pragma unroll
    for (int c=0;c<4;c++){
      s16x8 bf = *(const s16x8*)&Bls[(16*c+li)*40 + 8*lg];
      acc[c] = mfma16(af, bf, acc[c]);
    }
  }
  #pragma unroll
  for (int c=0;c<4;c++){
    int col = nbase + 16*c + li;
    float bv = bias[col];
    #pragma unroll
    for (int r=0;r<4;r++){
      int grow = mbase + 16*w + 4*lg + r;
      float val = acc[c][r] + bv;
      if (ROPE){
        int t = grow & (S_LEN-1);
        int d = col & 63;
        int i2 = d >> 1;
        float ang = (float)t * exp2f(-(float)i2 * 0.4152410118609203f); // log2(10000)/32
        float sv = sinf(ang), cv = cosf(ang);
        float other = __shfl_xor(val, 1);
        val = (d & 1) ? (other*sv + val*cv) : (val*cv - other*sv);
      }
      if (F32OUT) ((float*)Cv)[(size_t)grow*N + col] = val;
      else        ((ushort*)Cv)[(size_t)grow*N + col] = f2bf(val);
    }
  }
}

// ---------------- Fused GQA attention (two-pass exact softmax, writes attn_viz + seq) ----------------
__global__ __launch_bounds__(256) void attn_kernel(
    const ushort* __restrict__ qg, const ushort* __restrict__ kg, const ushort* __restrict__ vg,
    const int* __restrict__ lens, float* __restrict__ viz, ushort* __restrict__ seq){
  __shared__ ushort kls[64*72];
  __shared__ ushort vls[64*72];
  __shared__ ushort pls[64*72];
  int tid = threadIdx.x;
  int w = tid>>6, l = tid&63, lg = l>>4, li = l&15;
  int qbase = blockIdx.x*64;
  int qh = blockIdx.y;
  int n  = blockIdx.z;
  int h = qh>>2, H = qh&3;
  int len = lens[n];
  const float L2E = 1.4426950408889634f;

  int trow = qbase + 16*w + li;
  const ushort* qp = qg + ((size_t)n*S_LEN + trow)*1024 + qh*64 + 8*lg;
  s16x8 qf0 = *(const s16x8*)qp;
  s16x8 qf1 = *(const s16x8*)(qp + 32);

  int sT = tid>>2, sdg = (tid&3)*16;
  const ushort* kp = kg + ((size_t)n*S_LEN + sT)*256 + h*64 + sdg;
  const ushort* vp = vg + ((size_t)n*S_LEN + sT)*256 + h*64 + sdg;

  float m_r[4], l_r[4];
  #pragma unroll
  for (int r=0;r<4;r++){ m_r[r] = -1e30f; l_r[r] = 0.f; }
  int Tlim = min(qbase + 63, len - 1);
  int nComp = (Tlim >> 6) + 1;

  // ---- pass 1: running max / denom ----
  for (int it=0; it<nComp; ++it){
    int Tb = it*64;
    __syncthreads();
    { const ushort* kpp = kp + (size_t)Tb*256;
      *(s16x8*)&kls[sT*72 + sdg]     = *(const s16x8*)kpp;
      *(s16x8*)&kls[sT*72 + sdg + 8] = *(const s16x8*)(kpp + 8);
    }
    __syncthreads();
    f32x4 sc[4];
    #pragma unroll
    for (int c=0;c<4;c++) sc[c] = (f32x4){0.f,0.f,0.f,0.f};
    #pragma unroll
    for (int c=0;c<4;c++){
      s16x8 b0 = *(const s16x8*)&kls[(16*c+li)*72 + 8*lg];
      s16x8 b1 = *(const s16x8*)&kls[(16*c+li)*72 + 8*lg + 32];
      sc[c] = mfma16(qf0, b0, sc[c]);
      sc[c] = mfma16(qf1, b1, sc[c]);
    }
    #pragma unroll
    for (int c=0;c<4;c++){
      int Tg = Tb + 16*c + li;
      bool colp = Tg < len;
      #pragma unroll
      for (int r=0;r<4;r++){
        int tg = qbase + 16*w + 4*lg + r;
        sc[c][r] = (colp && Tg <= tg) ? sc[c][r]*0.125f : -1e30f;
      }
    }
    #pragma unroll
    for (int r=0;r<4;r++){
      float tmax = fmaxf(fmaxf(sc[0][r], sc[1][r]), fmaxf(sc[2][r], sc[3][r]));
      for (int msk=1; msk<16; msk<<=1) tmax = fmaxf(tmax, __shfl_xor(tmax, msk));
      float mn = fmaxf(m_r[r], tmax);
      float ssum = exp2f((sc[0][r]-mn)*L2E) + exp2f((sc[1][r]-mn)*L2E)
                 + exp2f((sc[2][r]-mn)*L2E) + exp2f((sc[3][r]-mn)*L2E);
      for (int msk=1; msk<16; msk<<=1) ssum += __shfl_xor(ssum, msk);
      l_r[r] = l_r[r]*exp2f((m_r[r]-mn)*L2E) + ssum;
      m_r[r] = mn;
    }
  }

  float inv_l[4];
  #pragma unroll
  for (int r=0;r<4;r++) inv_l[r] = 1.0f / l_r[r];

  f32x4 oacc[4];
  #pragma unroll
  for (int c=0;c<4;c++) oacc[c] = (f32x4){0.f,0.f,0.f,0.f};
  float* vizp = viz + (size_t)((n*4 + H)*4 + h) * S_LEN * S_LEN;

  // ---- pass 2: recompute scores, write p, PV ----
  for (int it=0; it<nComp; ++it){
    int Tb = it*64;
    __syncthreads();
    { const ushort* kpp = kp + (size_t)Tb*256;
      *(s16x8*)&kls[sT*72 + sdg]     = *(const s16x8*)kpp;
      *(s16x8*)&kls[sT*72 + sdg + 8] = *(const s16x8*)(kpp + 8);
      const ushort* vpp = vp + (size_t)Tb*256;
      s16x8 va = *(const s16x8*)vpp;
      s16x8 vb = *(const s16x8*)(vpp + 8);
      #pragma unroll
      for (int j=0;j<8;j++){
        vls[(sdg+j)*72 + sT]   = ((const ushort*)&va)[j];
        vls[(sdg+8+j)*72 + sT] = ((const ushort*)&vb)[j];
      }
    }
    __syncthreads();
    f32x4 sc[4];
    #pragma unroll
    for (int c=0;c<4;c++) sc[c] = (f32x4){0.f,0.f,0.f,0.f};
    #pragma unroll
    for (int c=0;c<4;c++){
      s16x8 b0 = *(const s16x8*)&kls[(16*c+li)*72 + 8*lg];
      s16x8 b1 = *(const s16x8*)&kls[(16*c+li)*72 + 8*lg + 32];
      sc[c] = mfma16(qf0, b0, sc[c]);
      sc[c] = mfma16(qf1, b1, sc[c]);
    }
    #pragma unroll
    for (int c=0;c<4;c++){
      int Tg = Tb + 16*c + li;
      bool colp = Tg < len;
      #pragma unroll
      for (int r=0;r<4;r++){
        int tg = qbase + 16*w + 4*lg + r;
        float s = (colp && Tg <= tg) ? sc[c][r]*0.125f : -1e30f;
        float p = exp2f((s - m_r[r])*L2E) * inv_l[r];
        vizp[(size_t)tg*S_LEN + Tg] = p;
        pls[(16*w + 4*lg + r)*72 + 16*c + li] = f2bf(p);
      }
    }
    #pragma unroll
    for (int f=0; f<2; f++){
      s16x8 pa = *(const s16x8*)&pls[(16*w + li)*72 + 8*lg + 32*f];
      #pragma unroll
      for (int c=0;c<4;c++){
        s16x8 vf = *(const s16x8*)&vls[(16*c+li)*72 + 8*lg + 32*f];
        oacc[c] = mfma16(pa, vf, oacc[c]);
      }
    }
  }

  // seq epilogue (bf16)
  #pragma unroll
  for (int c=0;c<4;c++){
    #pragma unroll
    for (int r=0;r<4;r++){
      int tg = qbase + 16*w + 4*lg + r;
      seq[((size_t)n*S_LEN + tg)*1024 + qh*64 + 16*c + li] = f2bf(oacc[c][r]);
    }
  }

  // zero-fill fully-masked tiles of attn_viz
  int zrow = qbase + 16*w + (l>>2);
  int zc = (l&3)*16;
  f32x4 zv = (f32x4){0.f,0.f,0.f,0.f};
  for (int it=nComp; it<(S_LEN/64); ++it){
    float* zp = vizp + (size_t)zrow*S_LEN + it*64 + zc;
    #pragma unroll
    for (int u=0;u<4;u++) *(f32x4*)(zp + 4*u) = zv;
  }
}

extern "C" void kernel_launch(void* const* d_in, const int* in_sizes, int n_in,
                              void* d_out, int out_size, void* d_ws, size_t ws_size,
                              hipStream_t stream){
  const float* xq = (const float*)d_in[0];
  const float* xk = (const float*)d_in[1];
  const float* xv = (const float*)d_in[2];
  const int*  lens= (const int*)d_in[3];
  const float* g  = (const float*)d_in[4];
  const float* be = (const float*)d_in[5];
  const float* Wq = (const float*)d_in[6];
  const float* bq = (const float*)d_in[7];
  const float* Wk = (const float*)d_in[8];
  const float* bk = (const float*)d_in[9];
  const float* Wv = (const float*)d_in[10];
  const float* bv = (const float*)d_in[11];
  const float* Wo = (const float*)d_in[12];
  const float* bo = (const float*)d_in[13];

  ushort* ws  = (ushort*)d_ws;
  ushort* xnq = ws;                    // 4096x1024 bf16
  ushort* xnk = ws + 4194304;
  ushort* xnv = ws + 8388608;
  ushort* qb  = ws + 12582912;         // 4096x1024
  ushort* kb  = ws + 16777216;         // 4096x256
  ushort* vb  = ws + 17825792;         // 4096x256
  ushort* WqT = ws + 18874368;         // 1024x1024
  ushort* WkT = ws + 19922944;         // 256x1024
  ushort* WvT = ws + 20185088;         // 256x1024
  ushort* WoT = ws + 20447232;         // 1024x1024
  ushort* seqb = xnq;                  // alias: xnq dead after q-proj

  float* outp = (float*)d_out;
  float* vizp = outp + (size_t)4194304;

  ln_kernel<<<4096,256,0,stream>>>(xq, g, be, xnq);
  ln_kernel<<<4096,256,0,stream>>>(xk, g, be, xnk);
  ln_kernel<<<4096,256,0,stream>>>(xv, g, be, xnv);
  wtr_kernel<<<4096,256,0,stream>>>(Wq, WqT, 10);
  wtr_kernel<<<1024,256,0,stream>>>(Wk, WkT, 8);
  wtr_kernel<<<1024,256,0,stream>>>(Wv, WvT, 8);
  wtr_kernel<<<4096,256,0,stream>>>(Wo, WoT, 10);
  gemm_kernel<true ,false><<<dim3(16,64),256,0,stream>>>(xnq, WqT, bq, qb, 1024, 1024);
  gemm_kernel<true ,false><<<dim3( 4,64),256,0,stream>>>(xnk, WkT, bk, kb,  256, 1024);
  gemm_kernel<false,false><<<dim3( 4,64),256,0,stream>>>(xnv, WvT, bv, vb,  256, 1024);
  attn_kernel<<<dim3(32,16,2),256,0,stream>>>(qb, kb, vb, lens, vizp, seqb);
  gemm_kernel<false,true ><<<dim3(16,64),256,0,stream>>>(seqb, WoT, bo, (void*)outp, 1024, 1024);
}